// Round 4
// 733.022 us; speedup vs baseline: 1.1643x; 1.1643x over previous
//
#include <hip/hip_runtime.h>
#include <hip/hip_bf16.h>

#define B_   8
#define C_   512
#define HW_  4096
#define M_   1024
#define N_   3072
#define EPS_ 1e-8f

typedef __attribute__((ext_vector_type(4))) float f32x4;
typedef __attribute__((ext_vector_type(8))) short short8;

// ---------------- K1: per-column inverse norms (all 4096 columns) ----------
__global__ void k_norms(const float* __restrict__ x, float* __restrict__ inv_all) {
    int blk = blockIdx.x;            // 256 blocks = 8 b * 32 chunks
    int b = blk >> 5;
    int chunk = blk & 31;
    int hw = chunk * 128 + threadIdx.x;   // 128 threads
    const float* xb = x + (size_t)b * C_ * HW_;
    float acc = 0.f;
#pragma unroll 8
    for (int c = 0; c < C_; ++c) {
        float v = xb[(size_t)c * HW_ + hw];
        acc = fmaf(v, v, acc);
    }
    inv_all[b * HW_ + hw] = 1.0f / (sqrtf(acc) + EPS_);
}

// ---------------- K2: pack x columns into bf16 hi/lo (uint32) rows ---------
// Layout: Apk[b][m][k] / Bpk[b][n][k], element = (lo16<<16)|hi16.
// Also emits dense inverse-norm arrays invM[b][1024], invC[b][3072].
// grid = 1024 blocks: first 256 = A (8b x 32 grp), next 768 = B (8b x 96 grp)
__global__ __launch_bounds__(256) void k_pack(const float* __restrict__ x,
    const int* __restrict__ nm_idx, const int* __restrict__ m_idx,
    const float* __restrict__ inv_all,
    unsigned int* __restrict__ Apk, unsigned int* __restrict__ Bpk,
    float* __restrict__ invM, float* __restrict__ invC)
{
    __shared__ float T[32][513];
    __shared__ int ps[32];
    int blk = blockIdx.x;
    int t = threadIdx.x;
    int isA = blk < 256;
    int b, grp;
    const int* idxarr;
    if (isA) { b = blk >> 5; grp = blk & 31; idxarr = m_idx; }
    else     { int r = blk - 256; b = r / 96; grp = r % 96; idxarr = nm_idx; }
    const float* xb = x + (size_t)b * C_ * HW_;
    if (t < 32) {
        int p = idxarr[grp * 32 + t];
        ps[t] = p;
        float iv = inv_all[b * HW_ + p];
        if (isA) invM[b * 1024 + grp * 32 + t] = iv;
        else     invC[b * 3072 + grp * 32 + t] = iv;
    }
    __syncthreads();
#pragma unroll 4
    for (int rep = 0; rep < 64; ++rep) {
        int idx = rep * 256 + t;
        int c = idx >> 5, i = idx & 31;
        T[i][c] = xb[(size_t)c * HW_ + ps[i]];
    }
    __syncthreads();
    unsigned int* dst = isA ? (Apk + ((size_t)b * 1024 + grp * 32) * 512)
                            : (Bpk + ((size_t)b * 3072 + grp * 32) * 512);
#pragma unroll 4
    for (int rep = 0; rep < 64; ++rep) {
        int idx = rep * 256 + t;
        int i = idx >> 9, c = idx & 511;
        float v = T[i][c];
        __hip_bfloat16 h = __float2bfloat16(v);
        float hf = __bfloat162float(h);
        __hip_bfloat16 l = __float2bfloat16(v - hf);
        unsigned int hi = __bfloat16_as_ushort(h);
        unsigned int lo = __bfloat16_as_ushort(l);
        dst[(size_t)i * 512 + c] = (lo << 16) | hi;
    }
}

// ---------------- K3: MFMA cos-sim GEMM (bf16-split) + per-row top-2 -------
// grid = 1536 blocks: b(8) x mt(8, 128 rows) x nt(24, 128 cols)
// block = 256 thr = 4 waves; wave w: wm=(w&1)*64, wn=(w>>1)*64; 4x4 16x16 tiles
__global__ __launch_bounds__(256, 2) void k_cosm(
    const unsigned int* __restrict__ Apk, const unsigned int* __restrict__ Bpk,
    const float* __restrict__ invM, const float* __restrict__ invC,
    float* __restrict__ pmax, int* __restrict__ pidx)
{
    __shared__ unsigned int As[128 * 36];   // [m][k] stride 36 (16B-aligned, balanced banks)
    __shared__ unsigned int Bs[128 * 36];
    __shared__ float sInvM[128];
    __shared__ float sInvC[128];

    int blk = blockIdx.x;
    int b  = blk / 192;
    int r  = blk % 192;
    int mt = r / 24;
    int nt = r % 24;
    int m0 = mt * 128, n0 = nt * 128;
    int t = threadIdx.x;
    int w = t >> 6, lane = t & 63;
    int wm = (w & 1) * 64, wn = (w >> 1) * 64;
    int quad = lane >> 4, nl = lane & 15;

    if (t < 128) sInvM[t] = invM[b * 1024 + m0 + t];
    else         sInvC[t - 128] = invC[b * 3072 + n0 + (t - 128)];

    const unsigned int* gA = Apk + ((size_t)b * 1024 + m0) * 512;
    const unsigned int* gB = Bpk + ((size_t)b * 3072 + n0) * 512;

    f32x4 acc[4][4];
#pragma unroll
    for (int i = 0; i < 4; ++i)
#pragma unroll
        for (int j = 0; j < 4; ++j) acc[i][j] = (f32x4){0.f, 0.f, 0.f, 0.f};

    for (int kt = 0; kt < 16; ++kt) {
        int k0 = kt * 32;
        __syncthreads();
#pragma unroll
        for (int rep = 0; rep < 4; ++rep) {
            int idx = rep * 1024 + t * 4;
            int row = idx >> 5, col = idx & 31;
            uint4 va = *(const uint4*)(gA + (size_t)row * 512 + k0 + col);
            uint4 vb = *(const uint4*)(gB + (size_t)row * 512 + k0 + col);
            *(uint4*)&As[row * 36 + col] = va;
            *(uint4*)&Bs[row * 36 + col] = vb;
        }
        __syncthreads();

        short8 ah[4], al[4], bh[4], bl[4];
#pragma unroll
        for (int mt2 = 0; mt2 < 4; ++mt2) {
            int m = wm + mt2 * 16 + nl;
            uint4 q0 = *(const uint4*)&As[m * 36 + quad * 8];
            uint4 q1 = *(const uint4*)&As[m * 36 + quad * 8 + 4];
            uint4 H, L;
            H.x = __builtin_amdgcn_perm(q0.y, q0.x, 0x05040100u);
            H.y = __builtin_amdgcn_perm(q0.w, q0.z, 0x05040100u);
            H.z = __builtin_amdgcn_perm(q1.y, q1.x, 0x05040100u);
            H.w = __builtin_amdgcn_perm(q1.w, q1.z, 0x05040100u);
            L.x = __builtin_amdgcn_perm(q0.y, q0.x, 0x07060302u);
            L.y = __builtin_amdgcn_perm(q0.w, q0.z, 0x07060302u);
            L.z = __builtin_amdgcn_perm(q1.y, q1.x, 0x07060302u);
            L.w = __builtin_amdgcn_perm(q1.w, q1.z, 0x07060302u);
            ah[mt2] = *(short8*)&H; al[mt2] = *(short8*)&L;
        }
#pragma unroll
        for (int nt2 = 0; nt2 < 4; ++nt2) {
            int n = wn + nt2 * 16 + nl;
            uint4 q0 = *(const uint4*)&Bs[n * 36 + quad * 8];
            uint4 q1 = *(const uint4*)&Bs[n * 36 + quad * 8 + 4];
            uint4 H, L;
            H.x = __builtin_amdgcn_perm(q0.y, q0.x, 0x05040100u);
            H.y = __builtin_amdgcn_perm(q0.w, q0.z, 0x05040100u);
            H.z = __builtin_amdgcn_perm(q1.y, q1.x, 0x05040100u);
            H.w = __builtin_amdgcn_perm(q1.w, q1.z, 0x05040100u);
            L.x = __builtin_amdgcn_perm(q0.y, q0.x, 0x07060302u);
            L.y = __builtin_amdgcn_perm(q0.w, q0.z, 0x07060302u);
            L.z = __builtin_amdgcn_perm(q1.y, q1.x, 0x07060302u);
            L.w = __builtin_amdgcn_perm(q1.w, q1.z, 0x07060302u);
            bh[nt2] = *(short8*)&H; bl[nt2] = *(short8*)&L;
        }
#pragma unroll
        for (int mt2 = 0; mt2 < 4; ++mt2)
#pragma unroll
            for (int nt2 = 0; nt2 < 4; ++nt2) {
                acc[mt2][nt2] = __builtin_amdgcn_mfma_f32_16x16x32_bf16(
                    ah[mt2], bh[nt2], acc[mt2][nt2], 0, 0, 0);
                acc[mt2][nt2] = __builtin_amdgcn_mfma_f32_16x16x32_bf16(
                    ah[mt2], bl[nt2], acc[mt2][nt2], 0, 0, 0);
                acc[mt2][nt2] = __builtin_amdgcn_mfma_f32_16x16x32_bf16(
                    al[mt2], bh[nt2], acc[mt2][nt2], 0, 0, 0);
            }
    }

    // epilogue: scale to cosine; per-lane top-2 across nt2; butterfly over 16 lanes
#pragma unroll
    for (int mt2 = 0; mt2 < 4; ++mt2)
#pragma unroll
        for (int reg = 0; reg < 4; ++reg) {
            int ml = wm + mt2 * 16 + quad * 4 + reg;
            float im = sInvM[ml];
            float v1 = -3.402823466e38f, v2 = -3.402823466e38f;
            int i1 = 0x7fffffff, i2 = 0x7fffffff;
#pragma unroll
            for (int nt2 = 0; nt2 < 4; ++nt2) {
                int nlc = wn + nt2 * 16 + nl;
                float v = acc[mt2][nt2][reg] * im * sInvC[nlc];
                int n = n0 + nlc;
                if (v > v1 || (v == v1 && n < i1)) { v2 = v1; i2 = i1; v1 = v; i1 = n; }
                else if (v > v2 || (v == v2 && n < i2)) { v2 = v; i2 = n; }
            }
#pragma unroll
            for (int off = 1; off < 16; off <<= 1) {
                float o1v = __shfl_xor(v1, off, 64); int o1i = __shfl_xor(i1, off, 64);
                float o2v = __shfl_xor(v2, off, 64); int o2i = __shfl_xor(i2, off, 64);
                if (o1v > v1 || (o1v == v1 && o1i < i1)) { v2 = v1; i2 = i1; v1 = o1v; i1 = o1i; }
                else if (o1v > v2 || (o1v == v2 && o1i < i2)) { v2 = o1v; i2 = o1i; }
                if (o2v > v1 || (o2v == v1 && o2i < i1)) { v2 = v1; i2 = i1; v1 = o2v; i1 = o2i; }
                else if (o2v > v2 || (o2v == v2 && o2i < i2)) { v2 = o2v; i2 = o2i; }
            }
            if (nl == 0) {
                int m_glob = (b << 10) + m0 + ml;
                int slot = nt * 2 + (w >> 1);
                int o = (m_glob * 48 + slot) * 2;
                pmax[o + 0] = v1; pidx[o + 0] = i1;
                pmax[o + 1] = v2; pidx[o + 1] = i2;
            }
        }
}

// ---------------- K4: combine partials + fp64 re-check near-ties -----------
__global__ void k_combine(const float* __restrict__ x,
    const int* __restrict__ nm_idx, const int* __restrict__ m_idx,
    const float* __restrict__ pmax, const int* __restrict__ pidx,
    float* __restrict__ maxc, int* __restrict__ bestp)
{
    int id = blockIdx.x * 256 + threadIdx.x;     // 8192
    int b = id >> 10, m = id & 1023;
    float v1 = -3.402823466e38f, v2 = -3.402823466e38f;
    int i1 = 0x7fffffff, i2 = 0x7fffffff;
#pragma unroll 8
    for (int r = 0; r < 96; ++r) {
        float v = pmax[(size_t)id * 96 + r];
        int   n = pidx[(size_t)id * 96 + r];
        if (v > v1 || (v == v1 && n < i1)) { v2 = v1; i2 = i1; v1 = v; i1 = n; }
        else if (v > v2 || (v == v2 && n < i2)) { v2 = v; i2 = n; }
    }
    if (v1 - v2 < 1e-4f) {
        // exact fp64 decision between the two candidates
        const float* xb = x + (size_t)b * C_ * HW_;
        int pm = m_idx[m], p1 = nm_idx[i1], p2 = nm_idx[i2];
        double smm = 0, s11 = 0, s22 = 0, sm1 = 0, sm2 = 0;
        for (int c = 0; c < C_; ++c) {
            double xm = xb[(size_t)c * HW_ + pm];
            double xa = xb[(size_t)c * HW_ + p1];
            double xc = xb[(size_t)c * HW_ + p2];
            smm += xm * xm; s11 += xa * xa; s22 += xc * xc;
            sm1 += xm * xa; sm2 += xm * xc;
        }
        double inv_m = 1.0 / (sqrt(smm) + 1e-8);
        double c1 = sm1 * inv_m / (sqrt(s11) + 1e-8);
        double c2 = sm2 * inv_m / (sqrt(s22) + 1e-8);
        if (c2 > c1 || (c2 == c1 && i2 < i1)) { v1 = v2; i1 = i2; }
    }
    maxc[id]  = v1;
    bestp[id] = nm_idx[i1];
}

// ---------------- K5: copy input -> output (context passthrough) -----------
__global__ void k_copy(const float4* __restrict__ in, float4* __restrict__ out) {
    int idx = blockIdx.x * 256 + threadIdx.x;
    int stride = gridDim.x * 256;
    for (int i = idx; i < (B_ * C_ * HW_ / 4); i += stride) out[i] = in[i];
}

// ---------------- K6: gather dense msk_n and best buffers ------------------
// grid = 256 blocks: b(8) x hole-row(32); block = 256 threads
__global__ __launch_bounds__(256) void k_gather(const float* __restrict__ x,
    const int* __restrict__ m_idx, const float* __restrict__ inv_all,
    const int* __restrict__ bestp, float* __restrict__ mskn, float* __restrict__ best)
{
    __shared__ float T[32][513];
    __shared__ int ps[32]; __shared__ float invm[32]; __shared__ int bp[32];
    int blk = blockIdx.x;
    int b = blk >> 5, row = blk & 31;
    int m0 = row * 32;
    int t = threadIdx.x;
    const float* xb = x + (size_t)b * C_ * HW_;
    if (t < 32) {
        int p = m_idx[m0 + t];
        ps[t] = p; invm[t] = inv_all[b * HW_ + p];
        bp[t] = bestp[(b << 10) + m0 + t];
    }
    __syncthreads();
#pragma unroll 4
    for (int rep = 0; rep < 64; ++rep) {
        int idx = rep * 256 + t;
        int c = idx >> 5, i = idx & 31;
        T[i][c] = xb[(size_t)c * HW_ + ps[i]];
    }
    __syncthreads();
#pragma unroll 4
    for (int rep = 0; rep < 64; ++rep) {
        int idx = rep * 256 + t;
        int i = idx >> 9, c = idx & 511;
        mskn[((size_t)(b << 10) + m0 + i) * C_ + c] = T[i][c] * invm[i];
    }
    for (int mi = 0; mi < 32; ++mi) {
        int p = bp[mi];
        size_t o = ((size_t)(b << 10) + m0 + mi) * C_;
        for (int c = t; c < C_; c += 256)
            best[o + c] = xb[(size_t)c * HW_ + p];
    }
}

// ---------------- DPP wave-64 sum: result broadcast via readlane(63) -------
__device__ __forceinline__ float wave_sum64(float x) {
    x += __int_as_float(__builtin_amdgcn_update_dpp(0, __float_as_int(x), 0x111, 0xf, 0xf, false));
    x += __int_as_float(__builtin_amdgcn_update_dpp(0, __float_as_int(x), 0x112, 0xf, 0xf, false));
    x += __int_as_float(__builtin_amdgcn_update_dpp(0, __float_as_int(x), 0x114, 0xf, 0xf, false));
    x += __int_as_float(__builtin_amdgcn_update_dpp(0, __float_as_int(x), 0x118, 0xf, 0xf, false));
    x += __int_as_float(__builtin_amdgcn_update_dpp(0, __float_as_int(x), 0x142, 0xa, 0xf, false));
    x += __int_as_float(__builtin_amdgcn_update_dpp(0, __float_as_int(x), 0x143, 0xc, 0xf, false));
    return __int_as_float(__builtin_amdgcn_readlane(__float_as_int(x), 63));
}

// ---------------- K7: sequential coherent scan (1 wave per batch) ----------
// v2: serial loop stripped to the recurrence only. Output written as
// CONTIGUOUS gen[b][m][c] (2KB coalesced wave-stores) -- the LDS transpose
// double-buffer + scattered out-stores are gone (they polluted the in-order
// vmcnt queue the 7-deep register prefetch waits on). Scatter to `out`
// happens in k_scatter afterwards (parallel, ~10us).
__global__ __launch_bounds__(64, 1) void k_scan(const float* __restrict__ mskn,
    const float* __restrict__ best, const float* __restrict__ maxc,
    float* __restrict__ gen)
{
    int b = blockIdx.x;
    int lane = threadIdx.x;
    const float4* mn4 = (const float4*)(mskn + (size_t)b * M_ * C_);
    const float4* bs4 = (const float4*)(best + (size_t)b * M_ * C_);
    const float* mx_p = maxc + b * M_;
    float4* gen4 = (float4*)(gen + (size_t)b * M_ * C_);

    float pr[8];
#pragma unroll
    for (int j = 0; j < 8; ++j) pr[j] = 0.f;

    // 8-slot register ring, prefetch distance 7 (identical to v1)
    float4 mf[8][2], bf[8][2]; float mx[8];
#pragma unroll
    for (int s = 0; s < 7; ++s) {
        int base = s * 128 + lane * 2;
        mf[s][0] = mn4[base]; mf[s][1] = mn4[base + 1];
        bf[s][0] = bs4[base]; bf[s][1] = bs4[base + 1];
        mx[s] = mx_p[s];
    }

    for (int mb = 0; mb < 128; ++mb) {
#pragma unroll
        for (int mi = 0; mi < 8; ++mi) {
            int m = mb * 8 + mi;
            int cur = mi;                 // compile-time ring index
            int nxt = (mi + 7) & 7;
            if (m + 7 < M_) {
                int base = (m + 7) * 128 + lane * 2;
                mf[nxt][0] = mn4[base]; mf[nxt][1] = mn4[base + 1];
                bf[nxt][0] = bs4[base]; bf[nxt][1] = bs4[base + 1];
                mx[nxt] = mx_p[m + 7];
            }
            float mn[8] = {mf[cur][0].x, mf[cur][0].y, mf[cur][0].z, mf[cur][0].w,
                           mf[cur][1].x, mf[cur][1].y, mf[cur][1].z, mf[cur][1].w};
            float bs[8] = {bf[cur][0].x, bf[cur][0].y, bf[cur][0].z, bf[cur][0].w,
                           bf[cur][1].x, bf[cur][1].y, bf[cur][1].z, bf[cur][1].w};
            float s1a = 0.f, s1b = 0.f, s2a = 0.f, s2b = 0.f;
#pragma unroll
            for (int j = 0; j < 4; ++j) {
                s1a = fmaf(pr[j], pr[j], s1a);
                s1b = fmaf(pr[j + 4], pr[j + 4], s1b);
                s2a = fmaf(mn[j], pr[j], s2a);
                s2b = fmaf(mn[j + 4], pr[j + 4], s2b);
            }
            float s1 = wave_sum64(s1a + s1b);
            float s2 = wave_sum64(s2a + s2b);
            float mxc = mx[cur];
            float d_ad = fmaxf(s2, 0.f) * __builtin_amdgcn_rcpf(sqrtf(s1) + EPS_);
            float inv  = __builtin_amdgcn_rcpf(d_ad + mxc + EPS_);
#pragma unroll
            for (int j = 0; j < 8; ++j)
                pr[j] = (d_ad * pr[j] + mxc * bs[j]) * inv;
            float4 o0 = {pr[0], pr[1], pr[2], pr[3]};
            float4 o1 = {pr[4], pr[5], pr[6], pr[7]};
            gen4[m * 128 + lane * 2]     = o0;   // contiguous 2KB wave store
            gen4[m * 128 + lane * 2 + 1] = o1;
        }
    }
}

// ---------------- K8: scatter gen[b][m][c] -> out[b][c][hole] --------------
// grid = 256 blocks: b(8) x hole-row(32); block = 256 threads.
// Hole columns of one hole-row are 32 CONTIGUOUS raster positions, so the
// write side is 128B-contiguous per channel.
__global__ __launch_bounds__(256) void k_scatter(const float* __restrict__ gen,
    const int* __restrict__ m_idx, float* __restrict__ out)
{
    __shared__ float T[32][513];
    int blk = blockIdx.x;
    int b = blk >> 5, row = blk & 31;
    int m0 = row * 32;
    int t = threadIdx.x;
#pragma unroll 4
    for (int rep = 0; rep < 64; ++rep) {
        int idx = rep * 256 + t;
        int i = idx >> 9, c = idx & 511;          // i in [0,32), c in [0,512)
        T[i][c] = gen[((size_t)(b << 10) + m0 + i) * C_ + c];
    }
    __syncthreads();
    int colg = m_idx[m0];                          // raster base of this hole row
    float* outb = out + (size_t)b * C_ * HW_;
#pragma unroll 4
    for (int rep = 0; rep < 64; ++rep) {
        int idx = rep * 256 + t;
        int c = idx >> 5, i = idx & 31;            // c in [0,512), i in [0,32)
        outb[(size_t)c * HW_ + colg + i] = T[i][c];
    }
}

// ---------------- launch ----------------------------------------------------
extern "C" void kernel_launch(void* const* d_in, const int* in_sizes, int n_in,
                              void* d_out, int out_size, void* d_ws, size_t ws_size,
                              hipStream_t stream) {
    (void)in_sizes; (void)n_in; (void)out_size; (void)ws_size;
    const float* x      = (const float*)d_in[0];
    const int*   nm_idx = (const int*)d_in[2];
    const int*   m_idx  = (const int*)d_in[3];
    float* out = (float*)d_out;
    char* ws = (char*)d_ws;

    float* inv_all = (float*)(ws + 0);              // 131072 B
    float* invM    = (float*)(ws + 131072);         // 32768 B
    float* invC    = (float*)(ws + 163840);         // 98304 B
    float* pmax    = (float*)(ws + 262144);         // 3,145,728 B [8192][48][2]
    int*   pidx    = (int*)  (ws + 3407872);        // 3,145,728 B
    float* maxc    = (float*)(ws + 6553600);        // 32768 B
    int*   bestp   = (int*)  (ws + 6586368);        // 32768 B
    unsigned int* Apk = (unsigned int*)(ws + 6619136);   // 16,777,216 B
    unsigned int* Bpk = (unsigned int*)(ws + 23396352);  // 50,331,648 B (end ~70.3 MB)
    // pack buffers are dead after k_cosm; mskn/best alias into them
    float* mskn = (float*)Apk;                      // 16 MB
    float* best = (float*)Bpk;                      // 16 MB (first third of Bpk region)
    // gen lives in the free tail of the Bpk region (Bpk dead after k_cosm;
    // best occupies only the first 16MB of the 48MB region)
    float* gen  = (float*)(ws + 23396352 + 16777216);    // 16 MB, end ~56.9 MB

    hipLaunchKernelGGL(k_norms,   dim3(256),  dim3(128), 0, stream, x, inv_all);
    hipLaunchKernelGGL(k_pack,    dim3(1024), dim3(256), 0, stream, x, nm_idx, m_idx, inv_all, Apk, Bpk, invM, invC);
    hipLaunchKernelGGL(k_cosm,    dim3(1536), dim3(256), 0, stream, Apk, Bpk, invM, invC, pmax, pidx);
    hipLaunchKernelGGL(k_combine, dim3(32),   dim3(256), 0, stream, x, nm_idx, m_idx, pmax, pidx, maxc, bestp);
    hipLaunchKernelGGL(k_copy,    dim3(2048), dim3(256), 0, stream, (const float4*)x, (float4*)out);
    hipLaunchKernelGGL(k_gather,  dim3(256),  dim3(256), 0, stream, x, m_idx, inv_all, bestp, mskn, best);
    hipLaunchKernelGGL(k_scan,    dim3(8),    dim3(64),  0, stream, mskn, best, maxc, gen);
    hipLaunchKernelGGL(k_scatter, dim3(256),  dim3(256), 0, stream, gen, m_idx, out);
}